// Round 3
// baseline (378.555 us; speedup 1.0000x reference)
//
#include <hip/hip_runtime.h>
#include <hip/hip_bf16.h>

// Problem constants (from reference)
#define C_FIELDS 12
#define F_FIELDS 4
#define SLOTS    16      // C + F
#define D_DIM    128

// Exclusive prefix sums of VOCABS = {100000,800,200,5000,60,30000,10,8,50,2000,20,16}
__device__ __constant__ int d_offsets[C_FIELDS] = {
    0, 100000, 100800, 101000, 106000, 106060,
    136060, 136070, 136078, 136128, 138128, 138148
};
__device__ __constant__ int d_vocabs[C_FIELDS] = {
    100000, 800, 200, 5000, 60, 30000, 10, 8, 50, 2000, 20, 16
};

// Dtype world (established R0-R2): cat=int32, cont/table/w/b=float32, out=float32.
// One output row = 128 fp32 = 512 B. 32 threads/row, one float4 (16 B) per
// thread. Block = 256 threads -> 8 rows/block. Coalesced loads + stores.
__global__ __launch_bounds__(256) void emb_fused_kernel(
    const int*   __restrict__ cat,     // [NTOK, 12] int32
    const float* __restrict__ cont,    // [NTOK, 4]
    const float* __restrict__ table,   // [V_TOTAL, 128]
    const float* __restrict__ wc,      // [4, 128]
    const float* __restrict__ bc,      // [4, 128]
    float*       __restrict__ out,     // [NTOK*16, 128]
    int n_rows)
{
    const int tid = blockIdx.x * blockDim.x + threadIdx.x;
    const int row = tid >> 5;                  // output row
    if (row >= n_rows) return;
    const int seg   = tid & 31;                // 16B-chunk within the row
    const int token = row >> 4;                // 16 slots per token
    const int slot  = row & 15;
    const int d0    = seg * 4;                 // fp32 element offset in D

    float4 result;
    if (slot < C_FIELDS) {
        int idx = cat[token * C_FIELDS + slot];
        // defensive clamp: keeps reads in-table under any index surprise
        if (idx < 0 || idx >= d_vocabs[slot]) idx = 0;
        if (idx == 0) {
            // torch padding_idx semantics: padding row of each field is zero
            result = make_float4(0.f, 0.f, 0.f, 0.f);
        } else {
            const size_t r = (size_t)(d_offsets[slot] + idx);
            result = *reinterpret_cast<const float4*>(table + r * D_DIM + d0);
        }
    } else {
        const int f = slot - C_FIELDS;
        const float x = cont[token * F_FIELDS + f];
        const float4 wv = *reinterpret_cast<const float4*>(wc + f * D_DIM + d0);
        const float4 bv = *reinterpret_cast<const float4*>(bc + f * D_DIM + d0);
        result.x = fmaf(x, wv.x, bv.x);
        result.y = fmaf(x, wv.y, bv.y);
        result.z = fmaf(x, wv.z, bv.z);
        result.w = fmaf(x, wv.w, bv.w);
    }
    *reinterpret_cast<float4*>(out + (size_t)row * D_DIM + d0) = result;
}

extern "C" void kernel_launch(void* const* d_in, const int* in_sizes, int n_in,
                              void* d_out, int out_size, void* d_ws, size_t ws_size,
                              hipStream_t stream) {
    const int*   cat   = (const int*)d_in[0];
    const float* cont  = (const float*)d_in[1];
    const float* table = (const float*)d_in[2];
    const float* wc    = (const float*)d_in[3];
    const float* bc    = (const float*)d_in[4];
    float*       out   = (float*)d_out;

    const int n_tok  = in_sizes[0] / C_FIELDS;   // B*L = 32768 (element count)
    const int n_rows = n_tok * SLOTS;            // 524288
    const long long total_threads = (long long)n_rows * 32;
    const int block = 256;
    const int grid = (int)((total_threads + block - 1) / block);

    emb_fused_kernel<<<grid, block, 0, stream>>>(cat, cont, table, wc, bc, out, n_rows);
}

// Round 4
// 356.051 us; speedup vs baseline: 1.0632x; 1.0632x over previous
//
#include <hip/hip_runtime.h>
#include <hip/hip_bf16.h>

// Problem constants (from reference)
#define C_FIELDS 12
#define F_FIELDS 4
#define SLOTS    16      // C + F
#define D_DIM    128

// Exclusive prefix sums of VOCABS = {100000,800,200,5000,60,30000,10,8,50,2000,20,16}
__device__ __constant__ int d_offsets[C_FIELDS] = {
    0, 100000, 100800, 101000, 106000, 106060,
    136060, 136070, 136078, 136128, 138128, 138148
};

using f32x4 = __attribute__((ext_vector_type(4))) float;

// Dtype world (established R0-R3): cat=int32, cont/table/w/b=float32, out=float32.
// One output row = 128 fp32 = 512 B. 32 threads/row, one float4 (16 B) per
// thread. Block = 256 threads -> 8 rows/block. Coalesced loads; NONTEMPORAL
// stores for the 268 MB write-once output stream so it doesn't evict the
// 70 MB gather table from L2/L3.
__global__ __launch_bounds__(256) void emb_fused_kernel(
    const int*   __restrict__ cat,     // [NTOK, 12] int32
    const float* __restrict__ cont,    // [NTOK, 4]
    const float* __restrict__ table,   // [V_TOTAL, 128]
    const float* __restrict__ wc,      // [4, 128]
    const float* __restrict__ bc,      // [4, 128]
    float*       __restrict__ out,     // [NTOK*16, 128]
    int n_rows)
{
    const int tid = blockIdx.x * blockDim.x + threadIdx.x;
    const int row = tid >> 5;                  // output row
    if (row >= n_rows) return;
    const int seg   = tid & 31;                // 16B-chunk within the row
    const int token = row >> 4;                // 16 slots per token
    const int slot  = row & 15;
    const int d0    = seg * 4;                 // fp32 element offset in D

    f32x4 result;
    if (slot < C_FIELDS) {
        const int idx = cat[token * C_FIELDS + slot];
        if (idx == 0) {
            // torch padding_idx semantics: padding row of each field is zero
            result = (f32x4){0.f, 0.f, 0.f, 0.f};
        } else {
            const size_t r = (size_t)(d_offsets[slot] + idx);
            result = *reinterpret_cast<const f32x4*>(table + r * D_DIM + d0);
        }
    } else {
        const int f = slot - C_FIELDS;
        const float x = cont[token * F_FIELDS + f];
        const f32x4 wv = *reinterpret_cast<const f32x4*>(wc + f * D_DIM + d0);
        const f32x4 bv = *reinterpret_cast<const f32x4*>(bc + f * D_DIM + d0);
        result.x = fmaf(x, wv.x, bv.x);
        result.y = fmaf(x, wv.y, bv.y);
        result.z = fmaf(x, wv.z, bv.z);
        result.w = fmaf(x, wv.w, bv.w);
    }
    // write-once output: nontemporal store (global_store_dwordx4 nt)
    __builtin_nontemporal_store(
        result, reinterpret_cast<f32x4*>(out + (size_t)row * D_DIM + d0));
}

extern "C" void kernel_launch(void* const* d_in, const int* in_sizes, int n_in,
                              void* d_out, int out_size, void* d_ws, size_t ws_size,
                              hipStream_t stream) {
    const int*   cat   = (const int*)d_in[0];
    const float* cont  = (const float*)d_in[1];
    const float* table = (const float*)d_in[2];
    const float* wc    = (const float*)d_in[3];
    const float* bc    = (const float*)d_in[4];
    float*       out   = (float*)d_out;

    const int n_tok  = in_sizes[0] / C_FIELDS;   // B*L = 32768 (element count)
    const int n_rows = n_tok * SLOTS;            // 524288
    const long long total_threads = (long long)n_rows * 32;
    const int block = 256;
    const int grid = (int)((total_threads + block - 1) / block);

    emb_fused_kernel<<<grid, block, 0, stream>>>(cat, cont, table, wc, bc, out, n_rows);
}